// Round 2
// baseline (1772.832 us; speedup 1.0000x reference)
//
#include <hip/hip_runtime.h>
#include <hip/hip_bf16.h>

// Block_45810121179249: 2x (single-head attn + residual + LayerNorm)
// B=4, S=4096, E=256. ALL inputs and the output are FP32 (per reference).
// Internal pipeline: bf16 MFMA with fp32 accumulation.
// ws layout (shorts): xb[4194304] (aliased by O1) | Wb[6*65536] | Qb | Kb | VTb
// total ~33 MB.

typedef __attribute__((ext_vector_type(8))) short bf16x8;  // 8 bf16 = 4 VGPRs
typedef __attribute__((ext_vector_type(4))) float f32x4;

#define MFMA_16x16x32(A, B, C) __builtin_amdgcn_mfma_f32_16x16x32_bf16(A, B, C, 0, 0, 0)

static __device__ __forceinline__ short f2bf(float f) {
    __hip_bfloat16 h = __float2bfloat16(f);
    return __builtin_bit_cast(short, h);
}
static __device__ __forceinline__ float bf2f(short s) {
    unsigned int u = ((unsigned int)(unsigned short)s) << 16;
    return __builtin_bit_cast(float, u);
}

// residual/output dtype helpers
static __device__ __forceinline__ float ld1(const float* p) { return *p; }
static __device__ __forceinline__ float ld1(const short* p) { return bf2f(*p); }
static __device__ __forceinline__ void st1(float* p, float v) { *p = v; }
static __device__ __forceinline__ void st1(short* p, float v) { *p = f2bf(v); }

// ---------------- fp32 -> bf16 conversion prepass ----------------
// Flat index over [x: 4194304][w0..w5: 65536 each] = 4,587,520 elems.
// Grid 2240 x 256 threads x 8 elems = exact cover, no bounds check.
__global__ __launch_bounds__(256) void cvt_all_kernel(
    const float* __restrict__ x,
    const float* __restrict__ w0, const float* __restrict__ w1,
    const float* __restrict__ w2, const float* __restrict__ w3,
    const float* __restrict__ w4, const float* __restrict__ w5,
    short* __restrict__ xb, short* __restrict__ wb)
{
    const int idx = (blockIdx.x * 256 + threadIdx.x) * 8;
    const float* src;
    short* dst;
    if (idx < 4194304) {
        src = x + idx;
        dst = xb + idx;
    } else {
        const int t = idx - 4194304;
        const int w = t >> 16, off = t & 65535;
        src = w0;
        if (w == 1) src = w1;
        else if (w == 2) src = w2;
        else if (w == 3) src = w3;
        else if (w == 4) src = w4;
        else if (w == 5) src = w5;
        src += off;
        dst = wb + w * 65536 + off;
    }
    float4 f0 = *reinterpret_cast<const float4*>(src);
    float4 f1 = *reinterpret_cast<const float4*>(src + 4);
    bf16x8 r;
    r[0] = f2bf(f0.x); r[1] = f2bf(f0.y); r[2] = f2bf(f0.z); r[3] = f2bf(f0.w);
    r[4] = f2bf(f1.x); r[5] = f2bf(f1.y); r[6] = f2bf(f1.z); r[7] = f2bf(f1.w);
    *reinterpret_cast<bf16x8*>(dst) = r;
}

// ---------------- QKV projection (all-bf16 in ws) ----------------
// Y = X @ W^T + b; Q,K stored [S,E] row-major bf16, V stored transposed [E,S].
// grid (256, 3): x = 64-row token tile, y = which of {Q,K,V}. 256 thr = 4 waves.
__global__ __launch_bounds__(256, 2) void qkv_proj_kernel(
    const short* __restrict__ X,
    const short* __restrict__ Wq, const float* __restrict__ bq,
    const short* __restrict__ Wk, const float* __restrict__ bk,
    const short* __restrict__ Wv, const float* __restrict__ bv,
    short* __restrict__ Qo, short* __restrict__ Ko, short* __restrict__ VTo)
{
    const int lane = threadIdx.x & 63;
    const int wave = threadIdx.x >> 6;
    const int c16  = lane & 15;
    const int quad = lane >> 4;
    const int which = blockIdx.y;
    const int m0 = blockIdx.x * 64 + wave * 16;   // 16-row strip per wave

    const short* W    = (which == 0) ? Wq : (which == 1) ? Wk : Wv;
    const float* bias = (which == 0) ? bq : (which == 1) ? bk : bv;

    // A-fragments: A[m=c16][k=quad*8+j], contiguous 16B along e
    bf16x8 a[8];
#pragma unroll
    for (int ke = 0; ke < 8; ++ke)
        a[ke] = *reinterpret_cast<const bf16x8*>(X + (m0 + c16) * 256 + ke * 32 + quad * 8);

    f32x4 acc[16];
#pragma unroll
    for (int nb = 0; nb < 16; ++nb) { f32x4 z = {0.f, 0.f, 0.f, 0.f}; acc[nb] = z; }

#pragma unroll
    for (int nb = 0; nb < 16; ++nb) {
        const short* wr = W + (nb * 16 + c16) * 256;   // B[k=e][n=o] = W[o][e]
#pragma unroll
        for (int ke = 0; ke < 8; ++ke) {
            bf16x8 b = *reinterpret_cast<const bf16x8*>(wr + ke * 32 + quad * 8);
            acc[nb] = MFMA_16x16x32(a[ke], b, acc[nb]);
        }
    }

    // D layout: row = quad*4 + r, col = c16 (m89/m91)
    if (which < 2) {
        short* dst = (which == 0) ? Qo : Ko;
#pragma unroll
        for (int nb = 0; nb < 16; ++nb) {
            const int o = nb * 16 + c16;
            const float bb_ = bias[o];
#pragma unroll
            for (int r = 0; r < 4; ++r) {
                const int row = m0 + quad * 4 + r;
                dst[row * 256 + o] = f2bf(acc[nb][r] + bb_);
            }
        }
    } else {
        // transposed store: 4 consecutive tokens per lane -> 8B packed store
#pragma unroll
        for (int nb = 0; nb < 16; ++nb) {
            const int o = nb * 16 + c16;
            const float bb_ = bias[o];
            const int row = m0 + quad * 4;     // first of 4 consecutive tokens
            const int batch = row >> 12;
            const int n = row & 4095;
            ushort4 pk;
            pk.x = (unsigned short)f2bf(acc[nb][0] + bb_);
            pk.y = (unsigned short)f2bf(acc[nb][1] + bb_);
            pk.z = (unsigned short)f2bf(acc[nb][2] + bb_);
            pk.w = (unsigned short)f2bf(acc[nb][3] + bb_);
            *reinterpret_cast<ushort4*>(VTo + (size_t)batch * (256 * 4096) + o * 4096 + n) = pk;
        }
    }
}

// ---------------- flash attention + residual + LayerNorm ----------------
// grid (4, 128): x = batch, y = 32-row q tile; 128 threads = 2 waves, each wave
// owns a 16-row q strip. No __syncthreads: P buffer is wave-private.
template <typename TRES, typename TOUT>
__global__ __launch_bounds__(128, 2) void attn_ln_kernel(
    const short* __restrict__ Qb, const short* __restrict__ Kb,
    const short* __restrict__ VTb,
    const TRES* __restrict__ res, const float* __restrict__ gamma,
    const float* __restrict__ beta, TOUT* __restrict__ out)
{
    // P: [16 rows][64 keys] per wave, row stride 72 (+16B pad -> <=2-way banks)
    __shared__ __attribute__((aligned(16))) short Plds[2 * 16 * 72];
    const int lane = threadIdx.x & 63;
    const int wave = threadIdx.x >> 6;
    const int c16  = lane & 15;
    const int quad = lane >> 4;
    const int batch = blockIdx.x;
    const int q0 = blockIdx.y * 32 + wave * 16;
    const size_t bb = (size_t)batch * (4096 * 256);

    // Q fragments stay in registers for the whole K loop (32 VGPRs)
    bf16x8 qf[8];
#pragma unroll
    for (int ke = 0; ke < 8; ++ke)
        qf[ke] = *reinterpret_cast<const bf16x8*>(Qb + bb + (q0 + c16) * 256 + ke * 32 + quad * 8);

    f32x4 o_acc[16];
#pragma unroll
    for (int nb = 0; nb < 16; ++nb) { f32x4 z = {0.f, 0.f, 0.f, 0.f}; o_acc[nb] = z; }
    float m[4], l[4];
#pragma unroll
    for (int r = 0; r < 4; ++r) { m[r] = -3.0e38f; l[r] = 0.f; }

    constexpr float SCALE = 1.0f / 64.0f;   // 1/sqrt(S=4096), per reference
    constexpr float LOG2E = 1.4426950408889634f;
    short* pb = Plds + wave * (16 * 72);

    for (int kt = 0; kt < 64; ++kt) {
        const int k0 = kt * 64;
        // ---- S = Q K^T for 64 keys: 4 n-blocks x 8 k-iters ----
        f32x4 s[4];
#pragma unroll
        for (int nb = 0; nb < 4; ++nb) { f32x4 z = {0.f, 0.f, 0.f, 0.f}; s[nb] = z; }
#pragma unroll
        for (int nb = 0; nb < 4; ++nb) {
            const short* kr = Kb + bb + (k0 + nb * 16 + c16) * 256;  // B[k=e][n=key]
#pragma unroll
            for (int ke = 0; ke < 8; ++ke) {
                bf16x8 kf = *reinterpret_cast<const bf16x8*>(kr + ke * 32 + quad * 8);
                s[nb] = MFMA_16x16x32(qf[ke], kf, s[nb]);
            }
        }

        // ---- online softmax (row = quad*4+r; 16 cols live across quad lanes) ----
        float p[4][4], alpha[4];
#pragma unroll
        for (int r = 0; r < 4; ++r) {
            float z0 = s[0][r] * SCALE, z1 = s[1][r] * SCALE;
            float z2 = s[2][r] * SCALE, z3 = s[3][r] * SCALE;
            float tmax = fmaxf(fmaxf(z0, z1), fmaxf(z2, z3));
            tmax = fmaxf(tmax, __shfl_xor(tmax, 1, 64));
            tmax = fmaxf(tmax, __shfl_xor(tmax, 2, 64));
            tmax = fmaxf(tmax, __shfl_xor(tmax, 4, 64));
            tmax = fmaxf(tmax, __shfl_xor(tmax, 8, 64));
            const float mn = fmaxf(m[r], tmax);
            alpha[r] = exp2f((m[r] - mn) * LOG2E);
            m[r] = mn;
            p[0][r] = exp2f((z0 - mn) * LOG2E);
            p[1][r] = exp2f((z1 - mn) * LOG2E);
            p[2][r] = exp2f((z2 - mn) * LOG2E);
            p[3][r] = exp2f((z3 - mn) * LOG2E);
            float rs = (p[0][r] + p[1][r]) + (p[2][r] + p[3][r]);
            rs += __shfl_xor(rs, 1, 64);
            rs += __shfl_xor(rs, 2, 64);
            rs += __shfl_xor(rs, 4, 64);
            rs += __shfl_xor(rs, 8, 64);
            l[r] = l[r] * alpha[r] + rs;
        }
#pragma unroll
        for (int nb = 0; nb < 16; ++nb) {
#pragma unroll
            for (int r = 0; r < 4; ++r) o_acc[nb][r] *= alpha[r];
        }

        // ---- P: D-layout -> LDS -> A-layout (m120-verified round trip) ----
#pragma unroll
        for (int nb = 0; nb < 4; ++nb)
#pragma unroll
            for (int r = 0; r < 4; ++r)
                pb[(quad * 4 + r) * 72 + nb * 16 + c16] = f2bf(p[nb][r]);

        bf16x8 ap0 = *reinterpret_cast<const bf16x8*>(pb + c16 * 72 + quad * 8);
        bf16x8 ap1 = *reinterpret_cast<const bf16x8*>(pb + c16 * 72 + 32 + quad * 8);

        // ---- O += P V : 16 e-blocks x 2 k-iters ----
#pragma unroll
        for (int nb = 0; nb < 16; ++nb) {
            const short* vr = VTb + bb + (nb * 16 + c16) * 4096 + k0 + quad * 8;
            bf16x8 v0 = *reinterpret_cast<const bf16x8*>(vr);       // keys k0..+31
            bf16x8 v1 = *reinterpret_cast<const bf16x8*>(vr + 32);  // keys +32..+63
            o_acc[nb] = MFMA_16x16x32(ap0, v0, o_acc[nb]);
            o_acc[nb] = MFMA_16x16x32(ap1, v1, o_acc[nb]);
        }
    }

    // ---- epilogue: /l, +residual, LayerNorm over E=256, store ----
    float rl[4];
#pragma unroll
    for (int r = 0; r < 4; ++r) rl[r] = 1.0f / l[r];

    float y[16][4];
#pragma unroll
    for (int nb = 0; nb < 16; ++nb) {
        const int colg = nb * 16 + c16;
#pragma unroll
        for (int r = 0; r < 4; ++r) {
            const int row = q0 + quad * 4 + r;
            y[nb][r] = o_acc[nb][r] * rl[r] + ld1(res + bb + row * 256 + colg);
        }
    }
#pragma unroll
    for (int r = 0; r < 4; ++r) {
        float sum = 0.f, sq = 0.f;
#pragma unroll
        for (int nb = 0; nb < 16; ++nb) { sum += y[nb][r]; sq += y[nb][r] * y[nb][r]; }
        sum += __shfl_xor(sum, 1, 64);  sq += __shfl_xor(sq, 1, 64);
        sum += __shfl_xor(sum, 2, 64);  sq += __shfl_xor(sq, 2, 64);
        sum += __shfl_xor(sum, 4, 64);  sq += __shfl_xor(sq, 4, 64);
        sum += __shfl_xor(sum, 8, 64);  sq += __shfl_xor(sq, 8, 64);
        const float mean = sum * (1.0f / 256.0f);
        const float var  = sq * (1.0f / 256.0f) - mean * mean;   // biased, = jnp.var
        const float rstd = rsqrtf(var + 1e-5f);
        const int row = q0 + quad * 4 + r;
#pragma unroll
        for (int nb = 0; nb < 16; ++nb) {
            const int colg = nb * 16 + c16;
            st1(out + bb + row * 256 + colg,
                (y[nb][r] - mean) * rstd * gamma[colg] + beta[colg]);
        }
    }
}

extern "C" void kernel_launch(void* const* d_in, const int* in_sizes, int n_in,
                              void* d_out, int out_size, void* d_ws, size_t ws_size,
                              hipStream_t stream) {
    const float* x   = (const float*)d_in[0];
    const float* Wq1 = (const float*)d_in[1];
    const float* bq1 = (const float*)d_in[2];
    const float* Wk1 = (const float*)d_in[3];
    const float* bk1 = (const float*)d_in[4];
    const float* Wv1 = (const float*)d_in[5];
    const float* bv1 = (const float*)d_in[6];
    const float* Wq2 = (const float*)d_in[7];
    const float* bq2 = (const float*)d_in[8];
    const float* Wk2 = (const float*)d_in[9];
    const float* bk2 = (const float*)d_in[10];
    const float* Wv2 = (const float*)d_in[11];
    const float* bv2 = (const float*)d_in[12];
    const float* g1  = (const float*)d_in[13];
    const float* be1 = (const float*)d_in[14];
    const float* g2  = (const float*)d_in[15];
    const float* be2 = (const float*)d_in[16];

    const size_t NE = (size_t)16384 * 256;   // B*S*E = 4,194,304
    short* xb  = (short*)d_ws;               // bf16 x; later aliased by O1
    short* Wb  = xb + NE;                    // 6 x 65536 bf16 weights
    short* Qb  = Wb + 6 * 65536;
    short* Kb  = Qb + NE;
    short* VTb = Kb + NE;
    short* O1  = xb;                         // alias: xb dead after qkv_proj #1
    float* outp = (float*)d_out;

    dim3 pgrid(256, 3), pblk(256);
    dim3 agrid(4, 128), ablk(128);

    cvt_all_kernel<<<2240, 256, 0, stream>>>(x, Wq1, Wk1, Wv1, Wq2, Wk2, Wv2, xb, Wb);
    qkv_proj_kernel<<<pgrid, pblk, 0, stream>>>(
        xb, Wb + 0 * 65536, bq1, Wb + 1 * 65536, bk1, Wb + 2 * 65536, bv1, Qb, Kb, VTb);
    attn_ln_kernel<float, short><<<agrid, ablk, 0, stream>>>(
        Qb, Kb, VTb, x, g1, be1, O1);
    qkv_proj_kernel<<<pgrid, pblk, 0, stream>>>(
        O1, Wb + 3 * 65536, bq2, Wb + 4 * 65536, bk2, Wb + 5 * 65536, bv2, Qb, Kb, VTb);
    attn_ln_kernel<short, float><<<agrid, ablk, 0, stream>>>(
        Qb, Kb, VTb, O1, g2, be2, outp);
}

// Round 3
// 560.158 us; speedup vs baseline: 3.1649x; 3.1649x over previous
//
#include <hip/hip_runtime.h>
#include <hip/hip_bf16.h>

// Block_45810121179249: 2x (single-head attn + residual + LayerNorm)
// B=4, S=4096, E=256. FP32 in/out; internal bf16 MFMA pipeline.
//
// Round 3: split-K flash attention with LDS-staged double-buffered K/V tiles
// (global_load_lds width=16, XOR-swizzled chunks), 4-wave blocks with 32 q-rows
// per wave (2 m-strips -> 2x fragment reuse), XCD-aware block decode, plus
// fp32 partial (O,m,l) + merge/LayerNorm kernel. Projection kernel now stages
// W in LDS (64 KB halves).

typedef __attribute__((ext_vector_type(8))) short bf16x8;  // 8 bf16 = 4 VGPRs
typedef __attribute__((ext_vector_type(4))) float f32x4;

#define MFMA_16x16x32(A, B, C) __builtin_amdgcn_mfma_f32_16x16x32_bf16(A, B, C, 0, 0, 0)

// async global->LDS, 16B per lane; LDS dest is wave-uniform base + lane*16
#define CP16(g, l)                                                              \
    __builtin_amdgcn_global_load_lds(                                           \
        (const __attribute__((address_space(1))) void*)(g),                     \
        (__attribute__((address_space(3))) void*)(l), 16, 0, 0)

static __device__ __forceinline__ short f2bf(float f) {
    __hip_bfloat16 h = __float2bfloat16(f);
    return __builtin_bit_cast(short, h);
}
static __device__ __forceinline__ float bf2f(short s) {
    unsigned int u = ((unsigned int)(unsigned short)s) << 16;
    return __builtin_bit_cast(float, u);
}
static __device__ __forceinline__ float ld1(const float* p) { return *p; }
static __device__ __forceinline__ float ld1(const short* p) { return bf2f(*p); }
static __device__ __forceinline__ void st1(float* p, float v) { *p = v; }
static __device__ __forceinline__ void st1(short* p, float v) { *p = f2bf(v); }

// ---- staging helpers -------------------------------------------------------
// Rows of 256 bf16 (512 B = 32 chunks of 16 B), XOR-swizzle chunk by (row&7).
// NCH256 rounds of 256 chunks; tid = 0..255.
template <int NCH256>
static __device__ __forceinline__ void stage_rows(const short* __restrict__ g,
                                                  short* s, int tid) {
    const int wave = tid >> 6;
#pragma unroll
    for (int j = 0; j < NCH256; ++j) {
        const int idx = j * 256 + tid;
        const int row = idx >> 5, c = idx & 31;
        CP16(g + row * 256 + ((c ^ (row & 7)) << 3),
             s + ((j * 256 + wave * 64) << 3));
    }
}
// VT tile: 256 e-rows x 64 keys (128 B = 8 chunks/row), global row stride 4096.
static __device__ __forceinline__ void stage_vt(const short* __restrict__ g,
                                                short* s, int tid) {
    const int wave = tid >> 6;
#pragma unroll
    for (int j = 0; j < 8; ++j) {
        const int idx = j * 256 + tid;
        const int e = idx >> 3, c = idx & 7;
        CP16(g + e * 4096 + ((c ^ (e & 7)) << 3),
             s + ((j * 256 + wave * 64) << 3));
    }
}

// ---------------- fp32 -> bf16 conversion prepass ----------------
__global__ __launch_bounds__(256) void cvt_all_kernel(
    const float* __restrict__ x,
    const float* __restrict__ w0, const float* __restrict__ w1,
    const float* __restrict__ w2, const float* __restrict__ w3,
    const float* __restrict__ w4, const float* __restrict__ w5,
    short* __restrict__ xb, short* __restrict__ wb)
{
    const int idx = (blockIdx.x * 256 + threadIdx.x) * 8;
    const float* src;
    short* dst;
    if (idx < 4194304) {
        src = x + idx;
        dst = xb + idx;
    } else {
        const int t = idx - 4194304;
        const int w = t >> 16, off = t & 65535;
        src = w0;
        if (w == 1) src = w1;
        else if (w == 2) src = w2;
        else if (w == 3) src = w3;
        else if (w == 4) src = w4;
        else if (w == 5) src = w5;
        src += off;
        dst = wb + w * 65536 + off;
    }
    float4 f0 = *reinterpret_cast<const float4*>(src);
    float4 f1 = *reinterpret_cast<const float4*>(src + 4);
    bf16x8 r;
    r[0] = f2bf(f0.x); r[1] = f2bf(f0.y); r[2] = f2bf(f0.z); r[3] = f2bf(f0.w);
    r[4] = f2bf(f1.x); r[5] = f2bf(f1.y); r[6] = f2bf(f1.z); r[7] = f2bf(f1.w);
    *reinterpret_cast<bf16x8*>(dst) = r;
}

// ---------------- QKV projection, W staged in LDS ----------------
// grid (256, 3): x = 64-row token tile, y = {Q,K,V}. 256 thr = 4 waves.
__global__ __launch_bounds__(256, 2) void qkv_proj_kernel(
    const short* __restrict__ X,
    const short* __restrict__ Wq, const float* __restrict__ bq,
    const short* __restrict__ Wk, const float* __restrict__ bk,
    const short* __restrict__ Wv, const float* __restrict__ bv,
    short* __restrict__ Qo, short* __restrict__ Ko, short* __restrict__ VTo)
{
    __shared__ __attribute__((aligned(16))) short Wt[128 * 256];  // 64 KB half
    const int tid  = threadIdx.x;
    const int lane = tid & 63;
    const int wave = tid >> 6;
    const int c16  = lane & 15;
    const int quad = lane >> 4;
    const int which = blockIdx.y;
    const int m0 = blockIdx.x * 64 + wave * 16;

    const short* W    = (which == 0) ? Wq : (which == 1) ? Wk : Wv;
    const float* bias = (which == 0) ? bq : (which == 1) ? bk : bv;

    bf16x8 a[8];
#pragma unroll
    for (int ke = 0; ke < 8; ++ke)
        a[ke] = *reinterpret_cast<const bf16x8*>(X + (m0 + c16) * 256 + ke * 32 + quad * 8);

    f32x4 acc[16];
#pragma unroll
    for (int nb = 0; nb < 16; ++nb) { f32x4 z = {0.f, 0.f, 0.f, 0.f}; acc[nb] = z; }

#pragma unroll
    for (int half = 0; half < 2; ++half) {
        if (half) __syncthreads();                 // done reading previous half
        stage_rows<16>(W + half * 128 * 256, Wt, tid);
        __syncthreads();                           // tile ready
#pragma unroll
        for (int nb8 = 0; nb8 < 8; ++nb8) {
            const int nb = half * 8 + nb8;
            const short* wr = Wt + (nb8 * 16 + c16) * 256;
#pragma unroll
            for (int ke = 0; ke < 8; ++ke) {
                bf16x8 b = *reinterpret_cast<const bf16x8*>(
                    wr + (((ke * 4 + quad) ^ (c16 & 7)) << 3));
                acc[nb] = MFMA_16x16x32(a[ke], b, acc[nb]);
            }
        }
    }

    if (which < 2) {
        short* dst = (which == 0) ? Qo : Ko;
#pragma unroll
        for (int nb = 0; nb < 16; ++nb) {
            const int o = nb * 16 + c16;
            const float bb_ = bias[o];
#pragma unroll
            for (int r = 0; r < 4; ++r)
                dst[(m0 + quad * 4 + r) * 256 + o] = f2bf(acc[nb][r] + bb_);
        }
    } else {
#pragma unroll
        for (int nb = 0; nb < 16; ++nb) {
            const int o = nb * 16 + c16;
            const float bb_ = bias[o];
            const int row = m0 + quad * 4;
            const int batch = row >> 12;
            const int n = row & 4095;
            ushort4 pk;
            pk.x = (unsigned short)f2bf(acc[nb][0] + bb_);
            pk.y = (unsigned short)f2bf(acc[nb][1] + bb_);
            pk.z = (unsigned short)f2bf(acc[nb][2] + bb_);
            pk.w = (unsigned short)f2bf(acc[nb][3] + bb_);
            *reinterpret_cast<ushort4*>(VTo + (size_t)batch * (256 * 4096) + o * 4096 + n) = pk;
        }
    }
}

// ---------------- split-K flash attention partial ----------------
// grid: 256 blocks, 1-D. bi&7 -> XCD; batch=(bi&7)>>1, ks=bi&1, qt=bi>>3.
// Block: 256 thr = 4 waves, each wave 32 q-rows (2 strips of 16).
// K/V 64-key tiles double-buffered in LDS (swizzled), 1 barrier per tile.
__global__ __launch_bounds__(256, 1) void attn_part_kernel(
    const short* __restrict__ Qb, const short* __restrict__ Kb,
    const short* __restrict__ VTb,
    float* __restrict__ Op, float* __restrict__ Mo, float* __restrict__ Lo)
{
    __shared__ __attribute__((aligned(16))) short Kt[2][64 * 256];   // 2x32 KB
    __shared__ __attribute__((aligned(16))) short Vt[2][256 * 64];   // 2x32 KB
    __shared__ __attribute__((aligned(16))) short Pb[4][32 * 72];    // 18 KB

    const int tid  = threadIdx.x;
    const int lane = tid & 63;
    const int wave = tid >> 6;
    const int c16  = lane & 15;
    const int quad = lane >> 4;
    const int bi = blockIdx.x;
    const int batch = (bi & 7) >> 1;
    const int ks    = bi & 1;
    const int qt    = bi >> 3;
    const size_t bb = (size_t)batch * (4096 * 256);
    const int rw = qt * 128 + wave * 32;          // wave's first q row
    const int kbase = ks * 2048;

    // Q fragments for both strips stay in registers (64 VGPRs)
    bf16x8 qf[2][8];
#pragma unroll
    for (int t = 0; t < 2; ++t)
#pragma unroll
        for (int ke = 0; ke < 8; ++ke)
            qf[t][ke] = *reinterpret_cast<const bf16x8*>(
                Qb + bb + (rw + t * 16 + c16) * 256 + ke * 32 + quad * 8);

    f32x4 oa[2][16];
#pragma unroll
    for (int t = 0; t < 2; ++t)
#pragma unroll
        for (int nb = 0; nb < 16; ++nb) { f32x4 z = {0.f, 0.f, 0.f, 0.f}; oa[t][nb] = z; }
    float m[2][4], l[2][4];
#pragma unroll
    for (int t = 0; t < 2; ++t)
#pragma unroll
        for (int r = 0; r < 4; ++r) { m[t][r] = -3.0e38f; l[t][r] = 0.f; }

    constexpr float SCALE = 1.0f / 64.0f;   // 1/sqrt(4096), per reference
    constexpr float LOG2E = 1.4426950408889634f;
    short* pw = &Pb[wave][0];

    // preload tile 0
    stage_rows<8>(Kb + bb + kbase * 256, &Kt[0][0], tid);
    stage_vt(VTb + bb + kbase, &Vt[0][0], tid);

    for (int kt = 0; kt < 32; ++kt) {
        __syncthreads();   // drains prefetch (overlapped with prev compute);
                           // also: all waves done with the other buffer
        if (kt + 1 < 32) {
            const int k0n = kbase + (kt + 1) * 64;
            stage_rows<8>(Kb + bb + k0n * 256, &Kt[(kt + 1) & 1][0], tid);
            stage_vt(VTb + bb + k0n, &Vt[(kt + 1) & 1][0], tid);
        }
        const short* K = &Kt[kt & 1][0];
        const short* V = &Vt[kt & 1][0];

        // ---- S = Q K^T (both strips share each K fragment) ----
        f32x4 s[2][4];
#pragma unroll
        for (int t = 0; t < 2; ++t)
#pragma unroll
            for (int nb = 0; nb < 4; ++nb) { f32x4 z = {0.f, 0.f, 0.f, 0.f}; s[t][nb] = z; }
#pragma unroll
        for (int nb = 0; nb < 4; ++nb) {
            const short* kr = K + (nb * 16 + c16) * 256;
#pragma unroll
            for (int ke = 0; ke < 8; ++ke) {
                bf16x8 kf = *reinterpret_cast<const bf16x8*>(
                    kr + (((ke * 4 + quad) ^ (c16 & 7)) << 3));
                s[0][nb] = MFMA_16x16x32(qf[0][ke], kf, s[0][nb]);
                s[1][nb] = MFMA_16x16x32(qf[1][ke], kf, s[1][nb]);
            }
        }

        // ---- online softmax per strip; P -> wave-private LDS ----
#pragma unroll
        for (int t = 0; t < 2; ++t) {
            float p[4][4], alpha[4];
#pragma unroll
            for (int r = 0; r < 4; ++r) {
                float z0 = s[t][0][r] * SCALE, z1 = s[t][1][r] * SCALE;
                float z2 = s[t][2][r] * SCALE, z3 = s[t][3][r] * SCALE;
                float tmax = fmaxf(fmaxf(z0, z1), fmaxf(z2, z3));
                tmax = fmaxf(tmax, __shfl_xor(tmax, 1, 64));
                tmax = fmaxf(tmax, __shfl_xor(tmax, 2, 64));
                tmax = fmaxf(tmax, __shfl_xor(tmax, 4, 64));
                tmax = fmaxf(tmax, __shfl_xor(tmax, 8, 64));
                const float mn = fmaxf(m[t][r], tmax);
                alpha[r] = exp2f((m[t][r] - mn) * LOG2E);
                m[t][r] = mn;
                p[0][r] = exp2f((z0 - mn) * LOG2E);
                p[1][r] = exp2f((z1 - mn) * LOG2E);
                p[2][r] = exp2f((z2 - mn) * LOG2E);
                p[3][r] = exp2f((z3 - mn) * LOG2E);
                float rs = (p[0][r] + p[1][r]) + (p[2][r] + p[3][r]);
                rs += __shfl_xor(rs, 1, 64);
                rs += __shfl_xor(rs, 2, 64);
                rs += __shfl_xor(rs, 4, 64);
                rs += __shfl_xor(rs, 8, 64);
                l[t][r] = l[t][r] * alpha[r] + rs;
            }
#pragma unroll
            for (int nb = 0; nb < 16; ++nb)
#pragma unroll
                for (int r = 0; r < 4; ++r) oa[t][nb][r] *= alpha[r];
#pragma unroll
            for (int nb = 0; nb < 4; ++nb)
#pragma unroll
                for (int r = 0; r < 4; ++r)
                    pw[(t * 16 + quad * 4 + r) * 72 + nb * 16 + c16] = f2bf(p[nb][r]);
        }

        // ---- A-fragments of P (both strips) ----
        bf16x8 ap[2][2];
#pragma unroll
        for (int t = 0; t < 2; ++t) {
            ap[t][0] = *reinterpret_cast<const bf16x8*>(pw + (t * 16 + c16) * 72 + quad * 8);
            ap[t][1] = *reinterpret_cast<const bf16x8*>(pw + (t * 16 + c16) * 72 + 32 + quad * 8);
        }

        // ---- O += P V (both strips share each V fragment) ----
#pragma unroll
        for (int nb = 0; nb < 16; ++nb) {
            const short* vr = V + (nb * 16 + c16) * 64;
            bf16x8 v0 = *reinterpret_cast<const bf16x8*>(
                vr + (((quad) ^ (c16 & 7)) << 3));          // keys 0..31
            bf16x8 v1 = *reinterpret_cast<const bf16x8*>(
                vr + (((quad + 4) ^ (c16 & 7)) << 3));      // keys 32..63
            oa[0][nb] = MFMA_16x16x32(ap[0][0], v0, oa[0][nb]);
            oa[0][nb] = MFMA_16x16x32(ap[0][1], v1, oa[0][nb]);
            oa[1][nb] = MFMA_16x16x32(ap[1][0], v0, oa[1][nb]);
            oa[1][nb] = MFMA_16x16x32(ap[1][1], v1, oa[1][nb]);
        }
    }

    // ---- write fp32 partials (unnormalized O, m, l) ----
#pragma unroll
    for (int t = 0; t < 2; ++t) {
#pragma unroll
        for (int r = 0; r < 4; ++r) {
            const int grow = rw + t * 16 + quad * 4 + r;
            const size_t ridx = (size_t)(ks * 4 + batch) * 4096 + grow;
#pragma unroll
            for (int nb = 0; nb < 16; ++nb)
                Op[ridx * 256 + nb * 16 + c16] = oa[t][nb][r];
            if (c16 == 0) { Mo[ridx] = m[t][r]; Lo[ridx] = l[t][r]; }
        }
    }
}

// ---------------- merge splits + residual + LayerNorm ----------------
// grid 4096 x 256 thr; each wave handles one row (E=256 = 64 lanes x 4).
template <typename TRES, typename TOUT>
__global__ __launch_bounds__(256) void merge_ln_kernel(
    const float* __restrict__ Op, const float* __restrict__ Mo,
    const float* __restrict__ Lo,
    const TRES* __restrict__ res, const float* __restrict__ gamma,
    const float* __restrict__ beta, TOUT* __restrict__ out)
{
    constexpr float LOG2E = 1.4426950408889634f;
    const int lane = threadIdx.x & 63;
    const int wave = threadIdx.x >> 6;
    const int row = blockIdx.x * 4 + wave;          // batch*4096 + local row
    const float m0 = Mo[row],         l0 = Lo[row];
    const float m1 = Mo[16384 + row], l1 = Lo[16384 + row];
    const float mm = fmaxf(m0, m1);
    const float a0 = exp2f((m0 - mm) * LOG2E);
    const float a1 = exp2f((m1 - mm) * LOG2E);
    const float li = 1.0f / (l0 * a0 + l1 * a1);

    const int e = lane * 4;
    float4 x0 = *reinterpret_cast<const float4*>(Op + (size_t)row * 256 + e);
    float4 x1 = *reinterpret_cast<const float4*>(Op + (size_t)(16384 + row) * 256 + e);
    float y[4];
    y[0] = (x0.x * a0 + x1.x * a1) * li + ld1(res + (size_t)row * 256 + e + 0);
    y[1] = (x0.y * a0 + x1.y * a1) * li + ld1(res + (size_t)row * 256 + e + 1);
    y[2] = (x0.z * a0 + x1.z * a1) * li + ld1(res + (size_t)row * 256 + e + 2);
    y[3] = (x0.w * a0 + x1.w * a1) * li + ld1(res + (size_t)row * 256 + e + 3);

    float sum = y[0] + y[1] + y[2] + y[3];
    float sq  = y[0]*y[0] + y[1]*y[1] + y[2]*y[2] + y[3]*y[3];
#pragma unroll
    for (int d = 1; d < 64; d <<= 1) {
        sum += __shfl_xor(sum, d, 64);
        sq  += __shfl_xor(sq,  d, 64);
    }
    const float mean = sum * (1.0f / 256.0f);
    const float var  = sq * (1.0f / 256.0f) - mean * mean;
    const float rstd = rsqrtf(var + 1e-5f);
#pragma unroll
    for (int i = 0; i < 4; ++i)
        st1(out + (size_t)row * 256 + e + i,
            (y[i] - mean) * rstd * gamma[e + i] + beta[e + i]);
}

extern "C" void kernel_launch(void* const* d_in, const int* in_sizes, int n_in,
                              void* d_out, int out_size, void* d_ws, size_t ws_size,
                              hipStream_t stream) {
    const float* x   = (const float*)d_in[0];
    const float* Wq1 = (const float*)d_in[1];
    const float* bq1 = (const float*)d_in[2];
    const float* Wk1 = (const float*)d_in[3];
    const float* bk1 = (const float*)d_in[4];
    const float* Wv1 = (const float*)d_in[5];
    const float* bv1 = (const float*)d_in[6];
    const float* Wq2 = (const float*)d_in[7];
    const float* bq2 = (const float*)d_in[8];
    const float* Wk2 = (const float*)d_in[9];
    const float* bk2 = (const float*)d_in[10];
    const float* Wv2 = (const float*)d_in[11];
    const float* bv2 = (const float*)d_in[12];
    const float* g1  = (const float*)d_in[13];
    const float* be1 = (const float*)d_in[14];
    const float* g2  = (const float*)d_in[15];
    const float* be2 = (const float*)d_in[16];

    const size_t NE = (size_t)16384 * 256;   // 4,194,304
    short* xb  = (short*)d_ws;               // bf16 x; aliased by O1 later
    short* Wb  = xb + NE;                    // 6 x 65536
    short* Qb  = Wb + 6 * 65536;
    short* Kb  = Qb + NE;
    short* VTb = Kb + NE;
    float* Op  = (float*)(VTb + NE);         // 2 x 16384 x 256 fp32
    float* Mo  = Op + 2 * NE;                // 2 x 16384
    float* Lo  = Mo + 2 * 16384;
    short* O1  = xb;                         // alias: xb dead after proj #1
    float* outp = (float*)d_out;

    dim3 pgrid(256, 3), pblk(256);

    cvt_all_kernel<<<2240, 256, 0, stream>>>(x, Wq1, Wk1, Wv1, Wq2, Wk2, Wv2, xb, Wb);

    qkv_proj_kernel<<<pgrid, pblk, 0, stream>>>(
        xb, Wb + 0 * 65536, bq1, Wb + 1 * 65536, bk1, Wb + 2 * 65536, bv1, Qb, Kb, VTb);
    attn_part_kernel<<<256, 256, 0, stream>>>(Qb, Kb, VTb, Op, Mo, Lo);
    merge_ln_kernel<float, short><<<4096, 256, 0, stream>>>(Op, Mo, Lo, x, g1, be1, O1);

    qkv_proj_kernel<<<pgrid, pblk, 0, stream>>>(
        O1, Wb + 3 * 65536, bq2, Wb + 4 * 65536, bk2, Wb + 5 * 65536, bv2, Qb, Kb, VTb);
    attn_part_kernel<<<256, 256, 0, stream>>>(Qb, Kb, VTb, Op, Mo, Lo);
    merge_ln_kernel<short, float><<<4096, 256, 0, stream>>>(Op, Mo, Lo, O1, g2, be2, outp);
}

// Round 4
// 351.052 us; speedup vs baseline: 5.0501x; 1.5957x over previous
//
#include <hip/hip_runtime.h>
#include <hip/hip_bf16.h>

// Block_45810121179249: 2x (single-head attn + residual + LayerNorm)
// B=4, S=4096, E=256. FP32 in/out; internal bf16 MFMA pipeline.
//
// Round 4: attn -> 512-thr blocks (8 waves, 2 waves/SIMD), split-K=4,
// fixed-reference softmax (p = exp2(z*log2e/64), no running max / no rescale:
// |z| <= ~10 by Cauchy-Schwarz so overflow impossible), per-lane l partials
// reduced once at the end, bf16 O partials merged by pure addition.

typedef __attribute__((ext_vector_type(8))) short bf16x8;  // 8 bf16 = 4 VGPRs
typedef __attribute__((ext_vector_type(4))) float f32x4;

#define MFMA_16x16x32(A, B, C) __builtin_amdgcn_mfma_f32_16x16x32_bf16(A, B, C, 0, 0, 0)

#define CP16(g, l)                                                              \
    __builtin_amdgcn_global_load_lds(                                           \
        (const __attribute__((address_space(1))) void*)(g),                     \
        (__attribute__((address_space(3))) void*)(l), 16, 0, 0)

static __device__ __forceinline__ short f2bf(float f) {
    __hip_bfloat16 h = __float2bfloat16(f);
    return __builtin_bit_cast(short, h);
}
static __device__ __forceinline__ float bf2f(short s) {
    unsigned int u = ((unsigned int)(unsigned short)s) << 16;
    return __builtin_bit_cast(float, u);
}
static __device__ __forceinline__ float ld1(const float* p) { return *p; }
static __device__ __forceinline__ float ld1(const short* p) { return bf2f(*p); }
static __device__ __forceinline__ void st1(float* p, float v) { *p = v; }
static __device__ __forceinline__ void st1(short* p, float v) { *p = f2bf(v); }

// ---- staging helpers (256-thread version, proj kernel) ---------------------
template <int NCH256>
static __device__ __forceinline__ void stage_rows(const short* __restrict__ g,
                                                  short* s, int tid) {
    const int wave = tid >> 6;
#pragma unroll
    for (int j = 0; j < NCH256; ++j) {
        const int idx = j * 256 + tid;
        const int row = idx >> 5, c = idx & 31;
        CP16(g + row * 256 + ((c ^ (row & 7)) << 3),
             s + ((j * 256 + wave * 64) << 3));
    }
}
// ---- staging helpers (512-thread version, attn kernel) ---------------------
// K tile: 64 rows x 256 e (32 chunks/row), chunk swizzled by row&7.
static __device__ __forceinline__ void stage_rows512(const short* __restrict__ g,
                                                     short* s, int tid) {
    const int wave = tid >> 6;
#pragma unroll
    for (int j = 0; j < 4; ++j) {
        const int idx = j * 512 + tid;
        const int row = idx >> 5, c = idx & 31;
        CP16(g + row * 256 + ((c ^ (row & 7)) << 3),
             s + ((j * 512 + wave * 64) << 3));
    }
}
// V tile: 256 e-rows x 64 keys (8 chunks/row), global row stride 4096.
static __device__ __forceinline__ void stage_vt512(const short* __restrict__ g,
                                                   short* s, int tid) {
    const int wave = tid >> 6;
#pragma unroll
    for (int j = 0; j < 4; ++j) {
        const int idx = j * 512 + tid;
        const int e = idx >> 3, c = idx & 7;
        CP16(g + e * 4096 + ((c ^ (e & 7)) << 3),
             s + ((j * 512 + wave * 64) << 3));
    }
}

// ---------------- fp32 -> bf16 conversion prepass ----------------
__global__ __launch_bounds__(256) void cvt_all_kernel(
    const float* __restrict__ x,
    const float* __restrict__ w0, const float* __restrict__ w1,
    const float* __restrict__ w2, const float* __restrict__ w3,
    const float* __restrict__ w4, const float* __restrict__ w5,
    short* __restrict__ xb, short* __restrict__ wb)
{
    const int idx = (blockIdx.x * 256 + threadIdx.x) * 8;
    const float* src;
    short* dst;
    if (idx < 4194304) {
        src = x + idx;
        dst = xb + idx;
    } else {
        const int t = idx - 4194304;
        const int w = t >> 16, off = t & 65535;
        src = w0;
        if (w == 1) src = w1;
        else if (w == 2) src = w2;
        else if (w == 3) src = w3;
        else if (w == 4) src = w4;
        else if (w == 5) src = w5;
        src += off;
        dst = wb + w * 65536 + off;
    }
    float4 f0 = *reinterpret_cast<const float4*>(src);
    float4 f1 = *reinterpret_cast<const float4*>(src + 4);
    bf16x8 r;
    r[0] = f2bf(f0.x); r[1] = f2bf(f0.y); r[2] = f2bf(f0.z); r[3] = f2bf(f0.w);
    r[4] = f2bf(f1.x); r[5] = f2bf(f1.y); r[6] = f2bf(f1.z); r[7] = f2bf(f1.w);
    *reinterpret_cast<bf16x8*>(dst) = r;
}

// ---------------- QKV projection, W staged in LDS ----------------
__global__ __launch_bounds__(256, 2) void qkv_proj_kernel(
    const short* __restrict__ X,
    const short* __restrict__ Wq, const float* __restrict__ bq,
    const short* __restrict__ Wk, const float* __restrict__ bk,
    const short* __restrict__ Wv, const float* __restrict__ bv,
    short* __restrict__ Qo, short* __restrict__ Ko, short* __restrict__ VTo)
{
    __shared__ __attribute__((aligned(16))) short Wt[128 * 256];  // 64 KB half
    const int tid  = threadIdx.x;
    const int lane = tid & 63;
    const int wave = tid >> 6;
    const int c16  = lane & 15;
    const int quad = lane >> 4;
    const int which = blockIdx.y;
    const int m0 = blockIdx.x * 64 + wave * 16;

    const short* W    = (which == 0) ? Wq : (which == 1) ? Wk : Wv;
    const float* bias = (which == 0) ? bq : (which == 1) ? bk : bv;

    bf16x8 a[8];
#pragma unroll
    for (int ke = 0; ke < 8; ++ke)
        a[ke] = *reinterpret_cast<const bf16x8*>(X + (m0 + c16) * 256 + ke * 32 + quad * 8);

    f32x4 acc[16];
#pragma unroll
    for (int nb = 0; nb < 16; ++nb) { f32x4 z = {0.f, 0.f, 0.f, 0.f}; acc[nb] = z; }

#pragma unroll
    for (int half = 0; half < 2; ++half) {
        if (half) __syncthreads();
        stage_rows<16>(W + half * 128 * 256, Wt, tid);
        __syncthreads();
#pragma unroll
        for (int nb8 = 0; nb8 < 8; ++nb8) {
            const int nb = half * 8 + nb8;
            const short* wr = Wt + (nb8 * 16 + c16) * 256;
#pragma unroll
            for (int ke = 0; ke < 8; ++ke) {
                bf16x8 b = *reinterpret_cast<const bf16x8*>(
                    wr + (((ke * 4 + quad) ^ (c16 & 7)) << 3));
                acc[nb] = MFMA_16x16x32(a[ke], b, acc[nb]);
            }
        }
    }

    if (which < 2) {
        short* dst = (which == 0) ? Qo : Ko;
#pragma unroll
        for (int nb = 0; nb < 16; ++nb) {
            const int o = nb * 16 + c16;
            const float bb_ = bias[o];
#pragma unroll
            for (int r = 0; r < 4; ++r)
                dst[(m0 + quad * 4 + r) * 256 + o] = f2bf(acc[nb][r] + bb_);
        }
    } else {
#pragma unroll
        for (int nb = 0; nb < 16; ++nb) {
            const int o = nb * 16 + c16;
            const float bb_ = bias[o];
            const int row = m0 + quad * 4;
            const int batch = row >> 12;
            const int n = row & 4095;
            ushort4 pk;
            pk.x = (unsigned short)f2bf(acc[nb][0] + bb_);
            pk.y = (unsigned short)f2bf(acc[nb][1] + bb_);
            pk.z = (unsigned short)f2bf(acc[nb][2] + bb_);
            pk.w = (unsigned short)f2bf(acc[nb][3] + bb_);
            *reinterpret_cast<ushort4*>(VTo + (size_t)batch * (256 * 4096) + o * 4096 + n) = pk;
        }
    }
}

// ---------------- split-K flash attention partial (fixed-ref softmax) -------
// grid 256 = 16 qt x (4 batch x 4 ks); bi%16 spreads (batch,ks) across XCDs.
// Block: 512 thr = 8 waves x 32 q-rows (2 strips) = 256 q-rows, 1024 keys.
__global__ __launch_bounds__(512, 2) void attn_part_kernel(
    const short* __restrict__ Qb, const short* __restrict__ Kb,
    const short* __restrict__ VTb,
    short* __restrict__ Op, float* __restrict__ Lo)
{
    __shared__ __attribute__((aligned(16))) short Kt[2][64 * 256];   // 2x32 KB
    __shared__ __attribute__((aligned(16))) short Vt[2][256 * 64];   // 2x32 KB
    __shared__ __attribute__((aligned(16))) short Pb[8][16 * 72];    // 18 KB

    const int tid  = threadIdx.x;
    const int lane = tid & 63;
    const int wave = tid >> 6;
    const int c16  = lane & 15;
    const int quad = lane >> 4;
    const int bi = blockIdx.x;
    const int batch = (bi >> 2) & 3;
    const int ks    = bi & 3;
    const int qt    = bi >> 4;
    const size_t bb = (size_t)batch * (4096 * 256);
    const int rw = qt * 256 + wave * 32;          // wave's first q row
    const int kbase = ks * 1024;

    // Q fragments for both strips stay in registers (64 VGPRs)
    bf16x8 qf[2][8];
#pragma unroll
    for (int t = 0; t < 2; ++t)
#pragma unroll
        for (int ke = 0; ke < 8; ++ke)
            qf[t][ke] = *reinterpret_cast<const bf16x8*>(
                Qb + bb + (rw + t * 16 + c16) * 256 + ke * 32 + quad * 8);

    f32x4 oa[2][16];
#pragma unroll
    for (int t = 0; t < 2; ++t)
#pragma unroll
        for (int nb = 0; nb < 16; ++nb) { f32x4 z = {0.f, 0.f, 0.f, 0.f}; oa[t][nb] = z; }
    float lsum[2][4];
#pragma unroll
    for (int t = 0; t < 2; ++t)
#pragma unroll
        for (int r = 0; r < 4; ++r) lsum[t][r] = 0.f;

    // p = exp2(z * log2(e)/64); fixed reference C=0 is exact for softmax
    constexpr float K1 = 1.4426950408889634f / 64.0f;
    short* pw = &Pb[wave][0];

    stage_rows512(Kb + bb + kbase * 256, &Kt[0][0], tid);
    stage_vt512(VTb + bb + kbase, &Vt[0][0], tid);

    for (int kt = 0; kt < 16; ++kt) {
        __syncthreads();   // all staging into buf[kt&1] complete; buf[(kt+1)&1] free
        if (kt + 1 < 16) {
            const int k0n = kbase + (kt + 1) * 64;
            stage_rows512(Kb + bb + k0n * 256, &Kt[(kt + 1) & 1][0], tid);
            stage_vt512(VTb + bb + k0n, &Vt[(kt + 1) & 1][0], tid);
        }
        const short* K = &Kt[kt & 1][0];
        const short* V = &Vt[kt & 1][0];

        // ---- S = Q K^T (both strips share each K fragment) ----
        f32x4 s[2][4];
#pragma unroll
        for (int t = 0; t < 2; ++t)
#pragma unroll
            for (int nb = 0; nb < 4; ++nb) { f32x4 z = {0.f, 0.f, 0.f, 0.f}; s[t][nb] = z; }
#pragma unroll
        for (int nb = 0; nb < 4; ++nb) {
            const short* kr = K + (nb * 16 + c16) * 256;
#pragma unroll
            for (int ke = 0; ke < 8; ++ke) {
                bf16x8 kf = *reinterpret_cast<const bf16x8*>(
                    kr + (((ke * 4 + quad) ^ (c16 & 7)) << 3));
                s[0][nb] = MFMA_16x16x32(qf[0][ke], kf, s[0][nb]);
                s[1][nb] = MFMA_16x16x32(qf[1][ke], kf, s[1][nb]);
            }
        }

        // ---- p = exp2(z*K1); accumulate per-lane l; P -> LDS; A-frags ----
        bf16x8 ap[2][2];
#pragma unroll
        for (int t = 0; t < 2; ++t) {
#pragma unroll
            for (int nb = 0; nb < 4; ++nb) {
#pragma unroll
                for (int r = 0; r < 4; ++r) {
                    const float pv = exp2f(s[t][nb][r] * K1);
                    lsum[t][r] += pv;
                    pw[(quad * 4 + r) * 72 + nb * 16 + c16] = f2bf(pv);
                }
            }
            // reads must complete before strip 1 overwrites (compiler lgkmcnt)
            ap[t][0] = *reinterpret_cast<const bf16x8*>(pw + c16 * 72 + quad * 8);
            ap[t][1] = *reinterpret_cast<const bf16x8*>(pw + c16 * 72 + 32 + quad * 8);
        }

        // ---- O += P V (both strips share each V fragment) ----
#pragma unroll
        for (int nb = 0; nb < 16; ++nb) {
            const short* vr = V + (nb * 16 + c16) * 64;
            bf16x8 v0 = *reinterpret_cast<const bf16x8*>(
                vr + ((quad ^ (c16 & 7)) << 3));            // keys 0..31
            bf16x8 v1 = *reinterpret_cast<const bf16x8*>(
                vr + (((quad + 4) ^ (c16 & 7)) << 3));      // keys 32..63
            oa[0][nb] = MFMA_16x16x32(ap[0][0], v0, oa[0][nb]);
            oa[0][nb] = MFMA_16x16x32(ap[0][1], v1, oa[0][nb]);
            oa[1][nb] = MFMA_16x16x32(ap[1][0], v0, oa[1][nb]);
            oa[1][nb] = MFMA_16x16x32(ap[1][1], v1, oa[1][nb]);
        }
    }

    // ---- reduce l across the 16 key-lanes; write bf16 partials ----
#pragma unroll
    for (int t = 0; t < 2; ++t) {
#pragma unroll
        for (int r = 0; r < 4; ++r) {
            float rs = lsum[t][r];
            rs += __shfl_xor(rs, 1, 64);
            rs += __shfl_xor(rs, 2, 64);
            rs += __shfl_xor(rs, 4, 64);
            rs += __shfl_xor(rs, 8, 64);
            const int grow = rw + t * 16 + quad * 4 + r;
            const size_t ridx = (size_t)ks * 16384 + batch * 4096 + grow;
#pragma unroll
            for (int nb = 0; nb < 16; ++nb)
                Op[ridx * 256 + nb * 16 + c16] = f2bf(oa[t][nb][r]);
            if (c16 == 0) Lo[ridx] = rs;
        }
    }
}

// ---------------- merge splits + residual + LayerNorm ----------------
// All splits share softmax frame C=0 -> merge is pure addition.
template <typename TRES, typename TOUT>
__global__ __launch_bounds__(256) void merge_ln_kernel(
    const short* __restrict__ Op, const float* __restrict__ Lo,
    const TRES* __restrict__ res, const float* __restrict__ gamma,
    const float* __restrict__ beta, TOUT* __restrict__ out)
{
    const int lane = threadIdx.x & 63;
    const int wave = threadIdx.x >> 6;
    const int row = blockIdx.x * 4 + wave;          // batch*4096 + local row
    const float li = 1.0f / (Lo[row] + Lo[16384 + row] +
                             Lo[32768 + row] + Lo[49152 + row]);
    const int e = lane * 4;
    float o[4] = {0.f, 0.f, 0.f, 0.f};
#pragma unroll
    for (int s = 0; s < 4; ++s) {
        ushort4 u = *reinterpret_cast<const ushort4*>(
            Op + ((size_t)s * 16384 + row) * 256 + e);
        o[0] += bf2f((short)u.x);
        o[1] += bf2f((short)u.y);
        o[2] += bf2f((short)u.z);
        o[3] += bf2f((short)u.w);
    }
    float y[4];
#pragma unroll
    for (int i = 0; i < 4; ++i)
        y[i] = o[i] * li + ld1(res + (size_t)row * 256 + e + i);

    float sum = y[0] + y[1] + y[2] + y[3];
    float sq  = y[0]*y[0] + y[1]*y[1] + y[2]*y[2] + y[3]*y[3];
#pragma unroll
    for (int d = 1; d < 64; d <<= 1) {
        sum += __shfl_xor(sum, d, 64);
        sq  += __shfl_xor(sq,  d, 64);
    }
    const float mean = sum * (1.0f / 256.0f);
    const float var  = sq * (1.0f / 256.0f) - mean * mean;
    const float rstd = rsqrtf(var + 1e-5f);
#pragma unroll
    for (int i = 0; i < 4; ++i)
        st1(out + (size_t)row * 256 + e + i,
            (y[i] - mean) * rstd * gamma[e + i] + beta[e + i]);
}

extern "C" void kernel_launch(void* const* d_in, const int* in_sizes, int n_in,
                              void* d_out, int out_size, void* d_ws, size_t ws_size,
                              hipStream_t stream) {
    const float* x   = (const float*)d_in[0];
    const float* Wq1 = (const float*)d_in[1];
    const float* bq1 = (const float*)d_in[2];
    const float* Wk1 = (const float*)d_in[3];
    const float* bk1 = (const float*)d_in[4];
    const float* Wv1 = (const float*)d_in[5];
    const float* bv1 = (const float*)d_in[6];
    const float* Wq2 = (const float*)d_in[7];
    const float* bq2 = (const float*)d_in[8];
    const float* Wk2 = (const float*)d_in[9];
    const float* bk2 = (const float*)d_in[10];
    const float* Wv2 = (const float*)d_in[11];
    const float* bv2 = (const float*)d_in[12];
    const float* g1  = (const float*)d_in[13];
    const float* be1 = (const float*)d_in[14];
    const float* g2  = (const float*)d_in[15];
    const float* be2 = (const float*)d_in[16];

    const size_t NE = (size_t)16384 * 256;   // 4,194,304
    short* xb  = (short*)d_ws;               // bf16 x; aliased by O1 later
    short* Wb  = xb + NE;                    // 6 x 65536
    short* Qb  = Wb + 6 * 65536;
    short* Kb  = Qb + NE;
    short* VTb = Kb + NE;
    short* Op  = VTb + NE;                   // 4 x 16384 x 256 bf16 = 32 MB
    float* Lo  = (float*)(Op + 4 * NE);      // 4 x 16384 fp32
    short* O1  = xb;                         // alias: xb dead after proj #1
    float* outp = (float*)d_out;

    dim3 pgrid(256, 3), pblk(256);

    cvt_all_kernel<<<2240, 256, 0, stream>>>(x, Wq1, Wk1, Wv1, Wq2, Wk2, Wv2, xb, Wb);

    qkv_proj_kernel<<<pgrid, pblk, 0, stream>>>(
        xb, Wb + 0 * 65536, bq1, Wb + 1 * 65536, bk1, Wb + 2 * 65536, bv1, Qb, Kb, VTb);
    attn_part_kernel<<<256, 512, 0, stream>>>(Qb, Kb, VTb, Op, Lo);
    merge_ln_kernel<float, short><<<4096, 256, 0, stream>>>(Op, Lo, x, g1, be1, O1);

    qkv_proj_kernel<<<pgrid, pblk, 0, stream>>>(
        O1, Wb + 3 * 65536, bq2, Wb + 4 * 65536, bk2, Wb + 5 * 65536, bv2, Qb, Kb, VTb);
    attn_part_kernel<<<256, 512, 0, stream>>>(Qb, Kb, VTb, Op, Lo);
    merge_ln_kernel<short, float><<<4096, 256, 0, stream>>>(Op, Lo, O1, g2, be2, outp);
}

// Round 5
// 332.950 us; speedup vs baseline: 5.3246x; 1.0544x over previous
//
#include <hip/hip_runtime.h>
#include <hip/hip_bf16.h>

// Block_45810121179249: 2x (single-head attn + residual + LayerNorm)
// B=4, S=4096, E=256. FP32 in/out; internal bf16 MFMA pipeline.
//
// Round 5: attn software pipelining (PV of tile kt-1 fills the QK(kt) MFMA
// drain; split barrier: __syncthreads at tile top for staging, raw s_barrier
// before V restage), XCD-local (batch,ks) decode for L2 residency, weights-only
// cvt prepass (proj#1 reads fp32 x directly).

typedef __attribute__((ext_vector_type(8))) short bf16x8;  // 8 bf16 = 4 VGPRs
typedef __attribute__((ext_vector_type(4))) float f32x4;

#define MFMA_16x16x32(A, B, C) __builtin_amdgcn_mfma_f32_16x16x32_bf16(A, B, C, 0, 0, 0)

#define CP16(g, l)                                                              \
    __builtin_amdgcn_global_load_lds(                                           \
        (const __attribute__((address_space(1))) void*)(g),                     \
        (__attribute__((address_space(3))) void*)(l), 16, 0, 0)

static __device__ __forceinline__ short f2bf(float f) {
    __hip_bfloat16 h = __float2bfloat16(f);
    return __builtin_bit_cast(short, h);
}
static __device__ __forceinline__ float bf2f(short s) {
    unsigned int u = ((unsigned int)(unsigned short)s) << 16;
    return __builtin_bit_cast(float, u);
}
static __device__ __forceinline__ float ld1(const float* p) { return *p; }
static __device__ __forceinline__ float ld1(const short* p) { return bf2f(*p); }
static __device__ __forceinline__ void st1(float* p, float v) { *p = v; }
static __device__ __forceinline__ void st1(short* p, float v) { *p = f2bf(v); }

// A-fragment load: bf16 direct, or fp32 with inline convert (proj#1)
static __device__ __forceinline__ bf16x8 ldA8(const short* p) {
    return *reinterpret_cast<const bf16x8*>(p);
}
static __device__ __forceinline__ bf16x8 ldA8(const float* p) {
    float4 f0 = *reinterpret_cast<const float4*>(p);
    float4 f1 = *reinterpret_cast<const float4*>(p + 4);
    bf16x8 r;
    r[0] = f2bf(f0.x); r[1] = f2bf(f0.y); r[2] = f2bf(f0.z); r[3] = f2bf(f0.w);
    r[4] = f2bf(f1.x); r[5] = f2bf(f1.y); r[6] = f2bf(f1.z); r[7] = f2bf(f1.w);
    return r;
}

// ---- staging helpers (256-thread version, proj kernel) ---------------------
template <int NCH256>
static __device__ __forceinline__ void stage_rows(const short* __restrict__ g,
                                                  short* s, int tid) {
    const int wave = tid >> 6;
#pragma unroll
    for (int j = 0; j < NCH256; ++j) {
        const int idx = j * 256 + tid;
        const int row = idx >> 5, c = idx & 31;
        CP16(g + row * 256 + ((c ^ (row & 7)) << 3),
             s + ((j * 256 + wave * 64) << 3));
    }
}
// ---- staging helpers (512-thread version, attn kernel) ---------------------
// K tile: 64 rows x 256 e (32 chunks/row), chunk swizzled by row&7.
static __device__ __forceinline__ void stage_k512(const short* __restrict__ g,
                                                  short* s, int tid) {
    const int wave = tid >> 6;
#pragma unroll
    for (int j = 0; j < 4; ++j) {
        const int idx = j * 512 + tid;
        const int row = idx >> 5, c = idx & 31;
        CP16(g + row * 256 + ((c ^ (row & 7)) << 3),
             s + ((j * 512 + wave * 64) << 3));
    }
}
// V tile: 256 e-rows x 64 keys (8 chunks/row), global row stride 4096.
static __device__ __forceinline__ void stage_v512(const short* __restrict__ g,
                                                  short* s, int tid) {
    const int wave = tid >> 6;
#pragma unroll
    for (int j = 0; j < 4; ++j) {
        const int idx = j * 512 + tid;
        const int e = idx >> 3, c = idx & 7;
        CP16(g + e * 4096 + ((c ^ (e & 7)) << 3),
             s + ((j * 512 + wave * 64) << 3));
    }
}

// ---------------- fp32 -> bf16 weight conversion (6 x 65536) ----------------
__global__ __launch_bounds__(256) void cvt_w_kernel(
    const float* __restrict__ w0, const float* __restrict__ w1,
    const float* __restrict__ w2, const float* __restrict__ w3,
    const float* __restrict__ w4, const float* __restrict__ w5,
    short* __restrict__ wb)
{
    const int idx = (blockIdx.x * 256 + threadIdx.x) * 8;   // grid 192 -> exact
    const int w = idx >> 16, off = idx & 65535;
    const float* src = w0;
    if (w == 1) src = w1;
    else if (w == 2) src = w2;
    else if (w == 3) src = w3;
    else if (w == 4) src = w4;
    else if (w == 5) src = w5;
    *reinterpret_cast<bf16x8*>(wb + w * 65536 + off) = ldA8(src + off);
}

// ---------------- QKV projection, W staged in LDS ----------------
// TX = float (layer 1, inline cvt) or short (layer 2).
template <typename TX>
__global__ __launch_bounds__(256, 2) void qkv_proj_kernel(
    const TX* __restrict__ X,
    const short* __restrict__ Wq, const float* __restrict__ bq,
    const short* __restrict__ Wk, const float* __restrict__ bk,
    const short* __restrict__ Wv, const float* __restrict__ bv,
    short* __restrict__ Qo, short* __restrict__ Ko, short* __restrict__ VTo)
{
    __shared__ __attribute__((aligned(16))) short Wt[128 * 256];  // 64 KB half
    const int tid  = threadIdx.x;
    const int lane = tid & 63;
    const int wave = tid >> 6;
    const int c16  = lane & 15;
    const int quad = lane >> 4;
    const int which = blockIdx.y;
    const int m0 = blockIdx.x * 64 + wave * 16;

    const short* W    = (which == 0) ? Wq : (which == 1) ? Wk : Wv;
    const float* bias = (which == 0) ? bq : (which == 1) ? bk : bv;

    bf16x8 a[8];
#pragma unroll
    for (int ke = 0; ke < 8; ++ke)
        a[ke] = ldA8(X + (m0 + c16) * 256 + ke * 32 + quad * 8);

    f32x4 acc[16];
#pragma unroll
    for (int nb = 0; nb < 16; ++nb) { f32x4 z = {0.f, 0.f, 0.f, 0.f}; acc[nb] = z; }

#pragma unroll
    for (int half = 0; half < 2; ++half) {
        if (half) __syncthreads();
        stage_rows<16>(W + half * 128 * 256, Wt, tid);
        __syncthreads();
#pragma unroll
        for (int nb8 = 0; nb8 < 8; ++nb8) {
            const int nb = half * 8 + nb8;
            const short* wr = Wt + (nb8 * 16 + c16) * 256;
#pragma unroll
            for (int ke = 0; ke < 8; ++ke) {
                bf16x8 b = *reinterpret_cast<const bf16x8*>(
                    wr + (((ke * 4 + quad) ^ (c16 & 7)) << 3));
                acc[nb] = MFMA_16x16x32(a[ke], b, acc[nb]);
            }
        }
    }

    if (which < 2) {
        short* dst = (which == 0) ? Qo : Ko;
#pragma unroll
        for (int nb = 0; nb < 16; ++nb) {
            const int o = nb * 16 + c16;
            const float bb_ = bias[o];
#pragma unroll
            for (int r = 0; r < 4; ++r)
                dst[(m0 + quad * 4 + r) * 256 + o] = f2bf(acc[nb][r] + bb_);
        }
    } else {
#pragma unroll
        for (int nb = 0; nb < 16; ++nb) {
            const int o = nb * 16 + c16;
            const float bb_ = bias[o];
            const int row = m0 + quad * 4;
            const int batch = row >> 12;
            const int n = row & 4095;
            ushort4 pk;
            pk.x = (unsigned short)f2bf(acc[nb][0] + bb_);
            pk.y = (unsigned short)f2bf(acc[nb][1] + bb_);
            pk.z = (unsigned short)f2bf(acc[nb][2] + bb_);
            pk.w = (unsigned short)f2bf(acc[nb][3] + bb_);
            *reinterpret_cast<ushort4*>(VTo + (size_t)batch * (256 * 4096) + o * 4096 + n) = pk;
        }
    }
}

// ---------------- split-K flash attention partial (pipelined) ---------------
// XCD-local decode: combo = ((bi&7)<<1)|(bi>>7) -> each XCD sees 2 (batch,ks)
// pairs = 2 MB K/V -> L2-resident. qt = (bi>>3)&15.
// Per tile kt: syncthreads -> stage K(kt+1) -> QK(kt) -> PV(kt-1) ->
// s_barrier -> stage V(kt+1) -> softmax/P/ap(kt). Final PV after loop.
__global__ __launch_bounds__(512, 2) void attn_part_kernel(
    const short* __restrict__ Qb, const short* __restrict__ Kb,
    const short* __restrict__ VTb,
    short* __restrict__ Op, float* __restrict__ Lo)
{
    __shared__ __attribute__((aligned(16))) short Kt[2][64 * 256];   // 2x32 KB
    __shared__ __attribute__((aligned(16))) short Vt[2][256 * 64];   // 2x32 KB
    __shared__ __attribute__((aligned(16))) short Pb[8][16 * 72];    // 18 KB

    const int tid  = threadIdx.x;
    const int lane = tid & 63;
    const int wave = tid >> 6;
    const int c16  = lane & 15;
    const int quad = lane >> 4;
    const int bi = blockIdx.x;
    const int combo = ((bi & 7) << 1) | ((bi >> 7) & 1);
    const int batch = combo >> 2;
    const int ks    = combo & 3;
    const int qt    = (bi >> 3) & 15;
    const size_t bb = (size_t)batch * (4096 * 256);
    const int rw = qt * 256 + wave * 32;          // wave's first q row
    const int kbase = ks * 1024;

    bf16x8 qf[2][8];
#pragma unroll
    for (int t = 0; t < 2; ++t)
#pragma unroll
        for (int ke = 0; ke < 8; ++ke)
            qf[t][ke] = *reinterpret_cast<const bf16x8*>(
                Qb + bb + (rw + t * 16 + c16) * 256 + ke * 32 + quad * 8);

    f32x4 oa[2][16];
#pragma unroll
    for (int t = 0; t < 2; ++t)
#pragma unroll
        for (int nb = 0; nb < 16; ++nb) { f32x4 z = {0.f, 0.f, 0.f, 0.f}; oa[t][nb] = z; }
    float lsum[2][4];
#pragma unroll
    for (int t = 0; t < 2; ++t)
#pragma unroll
        for (int r = 0; r < 4; ++r) lsum[t][r] = 0.f;

    constexpr float K1 = 1.4426950408889634f / 64.0f;  // log2(e)/sqrt(4096)
    short* pw = &Pb[wave][0];
    bf16x8 ap[2][2];   // P A-fragments, carried across iterations

    stage_k512(Kb + bb + kbase * 256, &Kt[0][0], tid);
    stage_v512(VTb + bb + kbase, &Vt[0][0], tid);

    for (int kt = 0; kt < 16; ++kt) {
        __syncthreads();   // staging of tile kt complete; K slot (kt+1)&1 free
        if (kt + 1 < 16)
            stage_k512(Kb + bb + (kbase + (kt + 1) * 64) * 256, &Kt[(kt + 1) & 1][0], tid);
        const short* K = &Kt[kt & 1][0];

        // ---- S = Q K^T (both strips share each K fragment) ----
        f32x4 s[2][4];
#pragma unroll
        for (int t = 0; t < 2; ++t)
#pragma unroll
            for (int nb = 0; nb < 4; ++nb) { f32x4 z = {0.f, 0.f, 0.f, 0.f}; s[t][nb] = z; }
#pragma unroll
        for (int nb = 0; nb < 4; ++nb) {
            const short* kr = K + (nb * 16 + c16) * 256;
#pragma unroll
            for (int ke = 0; ke < 8; ++ke) {
                bf16x8 kf = *reinterpret_cast<const bf16x8*>(
                    kr + (((ke * 4 + quad) ^ (c16 & 7)) << 3));
                s[0][nb] = MFMA_16x16x32(qf[0][ke], kf, s[0][nb]);
                s[1][nb] = MFMA_16x16x32(qf[1][ke], kf, s[1][nb]);
            }
        }

        // ---- PV of tile kt-1: operands ready, fills the QK MFMA drain ----
        if (kt > 0) {
            const short* V = &Vt[(kt - 1) & 1][0];
#pragma unroll
            for (int nb = 0; nb < 16; ++nb) {
                const short* vr = V + (nb * 16 + c16) * 64;
                bf16x8 v0 = *reinterpret_cast<const bf16x8*>(
                    vr + ((quad ^ (c16 & 7)) << 3));
                bf16x8 v1 = *reinterpret_cast<const bf16x8*>(
                    vr + (((quad + 4) ^ (c16 & 7)) << 3));
                oa[0][nb] = MFMA_16x16x32(ap[0][0], v0, oa[0][nb]);
                oa[0][nb] = MFMA_16x16x32(ap[0][1], v1, oa[0][nb]);
                oa[1][nb] = MFMA_16x16x32(ap[1][0], v0, oa[1][nb]);
                oa[1][nb] = MFMA_16x16x32(ap[1][1], v1, oa[1][nb]);
            }
        }

        // all waves' PV reads of V slot (kt-1)&1 are complete past this point;
        // no vmcnt drain here (raw barrier) so K prefetch stays in flight
        __builtin_amdgcn_s_barrier();
        if (kt + 1 < 16)
            stage_v512(VTb + bb + kbase + (kt + 1) * 64, &Vt[(kt + 1) & 1][0], tid);

        // ---- p = exp2(z*K1); per-lane l; P -> LDS; A-frags for next iter ----
#pragma unroll
        for (int t = 0; t < 2; ++t) {
#pragma unroll
            for (int nb = 0; nb < 4; ++nb) {
#pragma unroll
                for (int r = 0; r < 4; ++r) {
                    const float pv = exp2f(s[t][nb][r] * K1);
                    lsum[t][r] += pv;
                    pw[(quad * 4 + r) * 72 + nb * 16 + c16] = f2bf(pv);
                }
            }
            ap[t][0] = *reinterpret_cast<const bf16x8*>(pw + c16 * 72 + quad * 8);
            ap[t][1] = *reinterpret_cast<const bf16x8*>(pw + c16 * 72 + 32 + quad * 8);
        }
    }

    // ---- final PV (tile 15) ----
    {
        const short* V = &Vt[1][0];
#pragma unroll
        for (int nb = 0; nb < 16; ++nb) {
            const short* vr = V + (nb * 16 + c16) * 64;
            bf16x8 v0 = *reinterpret_cast<const bf16x8*>(
                vr + ((quad ^ (c16 & 7)) << 3));
            bf16x8 v1 = *reinterpret_cast<const bf16x8*>(
                vr + (((quad + 4) ^ (c16 & 7)) << 3));
            oa[0][nb] = MFMA_16x16x32(ap[0][0], v0, oa[0][nb]);
            oa[0][nb] = MFMA_16x16x32(ap[0][1], v1, oa[0][nb]);
            oa[1][nb] = MFMA_16x16x32(ap[1][0], v0, oa[1][nb]);
            oa[1][nb] = MFMA_16x16x32(ap[1][1], v1, oa[1][nb]);
        }
    }

    // ---- reduce l across the 16 key-lanes; write bf16 partials ----
#pragma unroll
    for (int t = 0; t < 2; ++t) {
#pragma unroll
        for (int r = 0; r < 4; ++r) {
            float rs = lsum[t][r];
            rs += __shfl_xor(rs, 1, 64);
            rs += __shfl_xor(rs, 2, 64);
            rs += __shfl_xor(rs, 4, 64);
            rs += __shfl_xor(rs, 8, 64);
            const int grow = rw + t * 16 + quad * 4 + r;
            const size_t ridx = (size_t)ks * 16384 + batch * 4096 + grow;
#pragma unroll
            for (int nb = 0; nb < 16; ++nb)
                Op[ridx * 256 + nb * 16 + c16] = f2bf(oa[t][nb][r]);
            if (c16 == 0) Lo[ridx] = rs;
        }
    }
}

// ---------------- merge splits + residual + LayerNorm ----------------
template <typename TRES, typename TOUT>
__global__ __launch_bounds__(256) void merge_ln_kernel(
    const short* __restrict__ Op, const float* __restrict__ Lo,
    const TRES* __restrict__ res, const float* __restrict__ gamma,
    const float* __restrict__ beta, TOUT* __restrict__ out)
{
    const int lane = threadIdx.x & 63;
    const int wave = threadIdx.x >> 6;
    const int row = blockIdx.x * 4 + wave;          // batch*4096 + local row
    const float li = 1.0f / (Lo[row] + Lo[16384 + row] +
                             Lo[32768 + row] + Lo[49152 + row]);
    const int e = lane * 4;
    float o[4] = {0.f, 0.f, 0.f, 0.f};
#pragma unroll
    for (int s = 0; s < 4; ++s) {
        ushort4 u = *reinterpret_cast<const ushort4*>(
            Op + ((size_t)s * 16384 + row) * 256 + e);
        o[0] += bf2f((short)u.x);
        o[1] += bf2f((short)u.y);
        o[2] += bf2f((short)u.z);
        o[3] += bf2f((short)u.w);
    }
    float y[4];
#pragma unroll
    for (int i = 0; i < 4; ++i)
        y[i] = o[i] * li + ld1(res + (size_t)row * 256 + e + i);

    float sum = y[0] + y[1] + y[2] + y[3];
    float sq  = y[0]*y[0] + y[1]*y[1] + y[2]*y[2] + y[3]*y[3];
#pragma unroll
    for (int d = 1; d < 64; d <<= 1) {
        sum += __shfl_xor(sum, d, 64);
        sq  += __shfl_xor(sq,  d, 64);
    }
    const float mean = sum * (1.0f / 256.0f);
    const float var  = sq * (1.0f / 256.0f) - mean * mean;
    const float rstd = rsqrtf(var + 1e-5f);
#pragma unroll
    for (int i = 0; i < 4; ++i)
        st1(out + (size_t)row * 256 + e + i,
            (y[i] - mean) * rstd * gamma[e + i] + beta[e + i]);
}

extern "C" void kernel_launch(void* const* d_in, const int* in_sizes, int n_in,
                              void* d_out, int out_size, void* d_ws, size_t ws_size,
                              hipStream_t stream) {
    const float* x   = (const float*)d_in[0];
    const float* Wq1 = (const float*)d_in[1];
    const float* bq1 = (const float*)d_in[2];
    const float* Wk1 = (const float*)d_in[3];
    const float* bk1 = (const float*)d_in[4];
    const float* Wv1 = (const float*)d_in[5];
    const float* bv1 = (const float*)d_in[6];
    const float* Wq2 = (const float*)d_in[7];
    const float* bq2 = (const float*)d_in[8];
    const float* Wk2 = (const float*)d_in[9];
    const float* bk2 = (const float*)d_in[10];
    const float* Wv2 = (const float*)d_in[11];
    const float* bv2 = (const float*)d_in[12];
    const float* g1  = (const float*)d_in[13];
    const float* be1 = (const float*)d_in[14];
    const float* g2  = (const float*)d_in[15];
    const float* be2 = (const float*)d_in[16];

    const size_t NE = (size_t)16384 * 256;   // 4,194,304
    short* O1  = (short*)d_ws;               // 8 MB (layer-1 output, bf16)
    short* Wb  = O1 + NE;                    // 6 x 65536
    short* Qb  = Wb + 6 * 65536;
    short* Kb  = Qb + NE;
    short* VTb = Kb + NE;
    short* Op  = VTb + NE;                   // 4 x 16384 x 256 bf16 = 32 MB
    float* Lo  = (float*)(Op + 4 * NE);      // 4 x 16384 fp32
    float* outp = (float*)d_out;

    dim3 pgrid(256, 3), pblk(256);

    cvt_w_kernel<<<192, 256, 0, stream>>>(Wq1, Wk1, Wv1, Wq2, Wk2, Wv2, Wb);

    qkv_proj_kernel<float><<<pgrid, pblk, 0, stream>>>(
        x, Wb + 0 * 65536, bq1, Wb + 1 * 65536, bk1, Wb + 2 * 65536, bv1, Qb, Kb, VTb);
    attn_part_kernel<<<256, 512, 0, stream>>>(Qb, Kb, VTb, Op, Lo);
    merge_ln_kernel<float, short><<<4096, 256, 0, stream>>>(Op, Lo, x, g1, be1, O1);

    qkv_proj_kernel<short><<<pgrid, pblk, 0, stream>>>(
        O1, Wb + 3 * 65536, bq2, Wb + 4 * 65536, bk2, Wb + 5 * 65536, bv2, Qb, Kb, VTb);
    attn_part_kernel<<<256, 512, 0, stream>>>(Qb, Kb, VTb, Op, Lo);
    merge_ln_kernel<short, float><<<4096, 256, 0, stream>>>(Op, Lo, O1, g2, be2, outp);
}